// Round 2
// baseline (835.051 us; speedup 1.0000x reference)
//
#include <hip/hip_runtime.h>
#include <math.h>

// Problem constants (from reference)
#define VOC 50000
#define DIM 128
#define B   256
#define CTX 8
#define K   10

#define NVEC (VOC / 4)          // 12500 float4 per one-hot row
#define N_VO  (B)               // 256 rows
#define N_VI  (B * CTX)         // 2048 rows
#define N_NEG (B * K)           // 2560 rows
#define NROW  (N_VO + N_VI + N_NEG)  // 4864 rows

#define ROWS_PER_BLOCK 4        // 4 independent waves per block, 1 row each

typedef float f32x4 __attribute__((ext_vector_type(4)));

// ---------------------------------------------------------------------------
// Kernel 1: find the index of the single nonzero in each one-hot row.
// One WAVE per row, scanning BIDIRECTIONALLY: per step, 8 float4/lane from
// the front + 8 float4/lane from the back (16 KB/step). Index uniform =>
// E[min(pos, N-pos)] = N/4, so expected bytes = 2 * N/4 = N/2 — same 50%
// floor as a forward scan — but the dependent load->ballot chain shrinks
// from 49 to 13 steps worst-case, cutting the latency-bound tail where the
// last far-index rows run nearly alone (~45us -> ~12us).
// Exactly ONE nonzero per row => any lane that sees it computes the same
// final index; duplicate reads from clamping/overlap are benign.
// ---------------------------------------------------------------------------
__global__ __launch_bounds__(256) void find_indices(
    const float* __restrict__ vo,
    const float* __restrict__ vi,
    const float* __restrict__ neg,
    int* __restrict__ out_idx)
{
    const int wave = threadIdx.x >> 6;     // 0..3
    const int lane = threadIdx.x & 63;     // 0..63
    const int r = blockIdx.x * ROWS_PER_BLOCK + wave;   // grid exact: 1216*4 == NROW

    const float* row;
    if (r < N_VO)              row = vo  + (size_t)r * VOC;
    else if (r < N_VO + N_VI)  row = vi  + (size_t)(r - N_VO) * VOC;
    else                       row = neg + (size_t)(r - N_VO - N_VI) * VOC;

    const f32x4* row4 = (const f32x4*)row;

    // 13 steps: front covers vec4 [0 .. 13*512-1 = 6655], back covers
    // [12499-6655 = 5844 .. 12499]; union covers the whole row.
    for (int s = 0; s < 13; ++s) {
        const int fb = s * 512 + lane;         // front: fb + j*64
        const int bb = (NVEC - 1) - fb;        // back:  bb - j*64

        f32x4 vf[8], vb[8];
#pragma unroll
        for (int j = 0; j < 8; ++j) {
            int p = fb + j * 64;
            p = (p < NVEC) ? p : (NVEC - 1);   // clamp: duplicate read, benign
            vf[j] = __builtin_nontemporal_load(&row4[p]);
        }
#pragma unroll
        for (int j = 0; j < 8; ++j) {
            int p = bb - j * 64;
            p = (p > 0) ? p : 0;               // clamp: duplicate read, benign
            vb[j] = __builtin_nontemporal_load(&row4[p]);
        }

        int  myp = -1;
        f32x4 mv = vf[0];
#pragma unroll
        for (int j = 0; j < 8; ++j) {
            const f32x4 a = vf[j];
            if (a.x != 0.f || a.y != 0.f || a.z != 0.f || a.w != 0.f) {
                int p = fb + j * 64;
                myp = (p < NVEC) ? p : (NVEC - 1);
                mv = a;
            }
            const f32x4 c = vb[j];
            if (c.x != 0.f || c.y != 0.f || c.z != 0.f || c.w != 0.f) {
                int p = bb - j * 64;
                myp = (p > 0) ? p : 0;
                mv = c;
            }
        }

        const unsigned long long m = __ballot(myp >= 0);
        if (m != 0ull) {                       // wave-uniform branch
            if (lane == __ffsll(m) - 1) {      // one writer (all would agree)
                const int off = (mv.x != 0.f) ? 0 : (mv.y != 0.f) ? 1
                              : (mv.z != 0.f) ? 2 : 3;
                out_idx[r] = 4 * myp + off;
            }
            break;
        }
    }
    // one-hot guaranteed by setup => always found; loss kernel clamps anyway.
}

// ---------------------------------------------------------------------------
// Kernel 2: per-batch-row loss. One wave per b; thread t owns dims {2t,2t+1}
// via float2 gathers. 11 wave-shuffle dot reductions, then one atomicAdd of
// -(left+right)/B into out[0].
// ---------------------------------------------------------------------------
__device__ __forceinline__ float wave_sum(float v) {
#pragma unroll
    for (int o = 32; o > 0; o >>= 1) v += __shfl_down(v, o);
    return v;   // valid in lane 0
}

__device__ __forceinline__ float log_sigmoid(float x) {
    // stable: min(x,0) - log1p(exp(-|x|))
    return fminf(x, 0.f) - log1pf(expf(-fabsf(x)));
}

__device__ __forceinline__ int clamp_idx(int i) {
    // idx workspace is never zeroed (harness poisons it) — clamp defensively
    // so a pathological unwritten slot can't cause an OOB gather.
    return i < 0 ? 0 : (i >= VOC ? VOC - 1 : i);
}

__global__ __launch_bounds__(64) void cbow_loss(
    const float* __restrict__ V,
    const float* __restrict__ U,
    const int* __restrict__ idx_all,
    float* __restrict__ out)
{
    const int b = blockIdx.x;     // 0..255
    const int t = threadIdx.x;    // 0..63

    const int* idx_vo  = idx_all;
    const int* idx_vi  = idx_all + N_VO;
    const int* idx_neg = idx_all + N_VO + N_VI;

    const int vo_i = clamp_idx(idx_vo[b]);
    const float2 v = ((const float2*)(V + (size_t)vo_i * DIM))[t];

    float2 e = make_float2(0.f, 0.f);
#pragma unroll
    for (int c = 0; c < CTX; ++c) {
        const int u = clamp_idx(idx_vi[b * CTX + c]);
        const float2 uu = ((const float2*)(U + (size_t)u * DIM))[t];
        e.x += uu.x;
        e.y += uu.y;
    }
    e.x *= (1.f / CTX);
    e.y *= (1.f / CTX);

    const float dot_pos = wave_sum(v.x * e.x + v.y * e.y);

    float right = 0.f;
#pragma unroll
    for (int k = 0; k < K; ++k) {
        const int u = clamp_idx(idx_neg[b * K + k]);
        const float2 uu = ((const float2*)(U + (size_t)u * DIM))[t];
        const float s = wave_sum(v.x * uu.x + v.y * uu.y);
        if (t == 0) right += log_sigmoid(-s);
    }

    if (t == 0) {
        const float left = log_sigmoid(dot_pos);
        atomicAdd(out, -(left + right) * (1.f / B));
    }
}

// ---------------------------------------------------------------------------
// Launch
// ---------------------------------------------------------------------------
extern "C" void kernel_launch(void* const* d_in, const int* in_sizes, int n_in,
                              void* d_out, int out_size, void* d_ws, size_t ws_size,
                              hipStream_t stream) {
    const float* vo  = (const float*)d_in[0];   // [B, VOC]
    const float* vi  = (const float*)d_in[1];   // [B, CTX, VOC]
    const float* neg = (const float*)d_in[2];   // [B, K, VOC]
    const float* V   = (const float*)d_in[3];   // [VOC, DIM]
    const float* U   = (const float*)d_in[4];   // [VOC, DIM]
    float* out = (float*)d_out;

    int* idx_ws = (int*)d_ws;                   // NROW ints = 19456 B

    // d_out is poisoned with 0xAA before every timed launch; zero it (async,
    // graph-capture safe).
    hipMemsetAsync(out, 0, sizeof(float), stream);

    find_indices<<<NROW / ROWS_PER_BLOCK, 256, 0, stream>>>(vo, vi, neg, idx_ws);
    cbow_loss<<<B, 64, 0, stream>>>(V, U, idx_ws, out);
}

// Round 3
// 825.841 us; speedup vs baseline: 1.0112x; 1.0112x over previous
//
#include <hip/hip_runtime.h>
#include <math.h>

// Problem constants (from reference)
#define VOC 50000
#define DIM 128
#define B   256
#define CTX 8
#define K   10

#define NVEC (VOC / 4)          // 12500 float4 per one-hot row
#define N_VO  (B)               // 256 rows
#define N_VI  (B * CTX)         // 2048 rows
#define N_NEG (B * K)           // 2560 rows
#define NROW  (N_VO + N_VI + N_NEG)  // 4864 rows

#define ROWS_PER_BLOCK 4        // 4 independent waves per block, 1 row each

typedef float f32x4 __attribute__((ext_vector_type(4)));

// ---------------------------------------------------------------------------
// Kernel 1: find the index of the single nonzero in each one-hot row.
// One WAVE (64 lanes) per row — no LDS, no __syncthreads in the hot loop.
// Per step: 4 nontemporal float4 loads/lane (step = 1024 floats = 4 KB/wave),
// then a single __ballot for the wave-uniform early exit. Expected read
// ~half of the 973 MB of one-hot data (information-theoretic floor for an
// adaptive search at cacheline granularity). All 4864 rows are resident as
// waves simultaneously (1216 blocks x 4 waves = 19 waves/CU < 32 capacity),
// so HBM stays saturated until the final rows complete — no serial tail.
// Round-2 lesson: bidirectional scan kept expected bytes but 4x'd the
// per-step overshoot granularity => small regression. Forward scan is best.
// Also zeroes out[0] (stream order puts cbow_loss's atomics after this
// kernel), eliminating the separate hipMemsetAsync dispatch.
// ---------------------------------------------------------------------------
__global__ __launch_bounds__(256) void find_indices(
    const float* __restrict__ vo,
    const float* __restrict__ vi,
    const float* __restrict__ neg,
    int* __restrict__ out_idx,
    float* __restrict__ out)
{
    if (blockIdx.x == 0 && threadIdx.x == 0) out[0] = 0.f;  // replaces memset

    const int wave = threadIdx.x >> 6;     // 0..3
    const int lane = threadIdx.x & 63;     // 0..63
    const int r = blockIdx.x * ROWS_PER_BLOCK + wave;   // grid exact: 1216*4 == NROW

    const float* row;
    if (r < N_VO)              row = vo  + (size_t)r * VOC;
    else if (r < N_VO + N_VI)  row = vi  + (size_t)(r - N_VO) * VOC;
    else                       row = neg + (size_t)(r - N_VO - N_VI) * VOC;

    const f32x4* row4 = (const f32x4*)row;

    // 49 steps max: ceil(12500 / 256). OOB lanes in the final step clamp to
    // the last vec4 — harmless: if the 1 lives there all clampers compute the
    // same index and __ffsll picks one writer; otherwise they read zeros.
    for (int s = 0; s < NVEC; s += 4 * 64) {
        f32x4 v[4];
#pragma unroll
        for (int j = 0; j < 4; ++j) {
            int p = s + j * 64 + lane;
            p = (p < NVEC) ? p : (NVEC - 1);
            v[j] = __builtin_nontemporal_load(&row4[p]);   // no L2 pollution
        }
        int found_j = -1;
#pragma unroll
        for (int j = 3; j >= 0; --j) {     // descending so smallest j wins
            if (v[j].x != 0.f || v[j].y != 0.f || v[j].z != 0.f || v[j].w != 0.f)
                found_j = j;
        }
        const unsigned long long m = __ballot(found_j >= 0);
        if (m != 0ull) {                   // wave-uniform branch
            if (lane == __ffsll(m) - 1) {  // exactly one writer
                int p = s + found_j * 64 + lane;
                p = (p < NVEC) ? p : (NVEC - 1);
                const f32x4 u = v[found_j];
                const int off = (u.x != 0.f) ? 0 : (u.y != 0.f) ? 1
                              : (u.z != 0.f) ? 2 : 3;
                out_idx[r] = 4 * p + off;
            }
            break;
        }
    }
    // one-hot guaranteed by setup => always found; loss kernel clamps anyway.
}

// ---------------------------------------------------------------------------
// Kernel 2: per-batch-row loss. One wave per b; thread t owns dims {2t,2t+1}
// via float2 gathers. 11 wave-shuffle dot reductions, then one atomicAdd of
// -(left+right)/B into out[0].
// ---------------------------------------------------------------------------
__device__ __forceinline__ float wave_sum(float v) {
#pragma unroll
    for (int o = 32; o > 0; o >>= 1) v += __shfl_down(v, o);
    return v;   // valid in lane 0
}

__device__ __forceinline__ float log_sigmoid(float x) {
    // stable: min(x,0) - log1p(exp(-|x|))
    return fminf(x, 0.f) - log1pf(expf(-fabsf(x)));
}

__device__ __forceinline__ int clamp_idx(int i) {
    // idx workspace is never zeroed (harness poisons it) — clamp defensively
    // so a pathological unwritten slot can't cause an OOB gather.
    return i < 0 ? 0 : (i >= VOC ? VOC - 1 : i);
}

__global__ __launch_bounds__(64) void cbow_loss(
    const float* __restrict__ V,
    const float* __restrict__ U,
    const int* __restrict__ idx_all,
    float* __restrict__ out)
{
    const int b = blockIdx.x;     // 0..255
    const int t = threadIdx.x;    // 0..63

    const int* idx_vo  = idx_all;
    const int* idx_vi  = idx_all + N_VO;
    const int* idx_neg = idx_all + N_VO + N_VI;

    const int vo_i = clamp_idx(idx_vo[b]);
    const float2 v = ((const float2*)(V + (size_t)vo_i * DIM))[t];

    float2 e = make_float2(0.f, 0.f);
#pragma unroll
    for (int c = 0; c < CTX; ++c) {
        const int u = clamp_idx(idx_vi[b * CTX + c]);
        const float2 uu = ((const float2*)(U + (size_t)u * DIM))[t];
        e.x += uu.x;
        e.y += uu.y;
    }
    e.x *= (1.f / CTX);
    e.y *= (1.f / CTX);

    const float dot_pos = wave_sum(v.x * e.x + v.y * e.y);

    float right = 0.f;
#pragma unroll
    for (int k = 0; k < K; ++k) {
        const int u = clamp_idx(idx_neg[b * K + k]);
        const float2 uu = ((const float2*)(U + (size_t)u * DIM))[t];
        const float s = wave_sum(v.x * uu.x + v.y * uu.y);
        if (t == 0) right += log_sigmoid(-s);
    }

    if (t == 0) {
        const float left = log_sigmoid(dot_pos);
        atomicAdd(out, -(left + right) * (1.f / B));
    }
}

// ---------------------------------------------------------------------------
// Launch
// ---------------------------------------------------------------------------
extern "C" void kernel_launch(void* const* d_in, const int* in_sizes, int n_in,
                              void* d_out, int out_size, void* d_ws, size_t ws_size,
                              hipStream_t stream) {
    const float* vo  = (const float*)d_in[0];   // [B, VOC]
    const float* vi  = (const float*)d_in[1];   // [B, CTX, VOC]
    const float* neg = (const float*)d_in[2];   // [B, K, VOC]
    const float* V   = (const float*)d_in[3];   // [VOC, DIM]
    const float* U   = (const float*)d_in[4];   // [VOC, DIM]
    float* out = (float*)d_out;

    int* idx_ws = (int*)d_ws;                   // NROW ints = 19456 B

    // out[0] is zeroed by find_indices (stream-ordered before cbow_loss's
    // atomics) — no separate memset dispatch needed.
    find_indices<<<NROW / ROWS_PER_BLOCK, 256, 0, stream>>>(vo, vi, neg, idx_ws, out);
    cbow_loss<<<B, 64, 0, stream>>>(V, U, idx_ws, out);
}